// Round 5
// baseline (158.555 us; speedup 1.0000x reference)
//
#include <hip/hip_runtime.h>

// Causal GQA attention, MI355X (gfx950). B=2,H=16,Hkv=4,S=2048,D=128 fp32.
// R5: software-pipelined K-loop in 64 KB LDS: K double-buffered, V single,
// P unpadded + XOR-chunk swizzle. Round = issue V(t),K(t+1) -> QK+softmax ->
// barrier (drain overlapped by ~1000 cyc of compute) -> PV -> barrier.
// Fixed-shift softmax (exp2, no running max), bf16 MFMA 16x16x32,
// work-balanced (qt,15-qt) 1D grid, prepacked bf16 K/V images in d_ws.

#define S_LEN 2048
#define DH    128
#define NH    16
#define NKVH  4
#define NB    2
#define TQ    128
#define TK    64
#define NQT   (S_LEN / TQ)   // 16
#define QSCALE 0.12752749610559243f   // (1/sqrt(128)) * log2(e)

typedef __attribute__((ext_vector_type(8))) short short8;
typedef __attribute__((ext_vector_type(4))) float f32x4;

#if __has_builtin(__builtin_amdgcn_exp2f)
#define EX2(x) __builtin_amdgcn_exp2f(x)
#else
#define EX2(x) exp2f(x)
#endif

__device__ __forceinline__ unsigned short bf1(float a) {
    union { float f; unsigned u; } x; x.f = a;
    return (unsigned short)((x.u + 0x8000u) >> 16);
}
__device__ __forceinline__ unsigned pk2(float a, float b) {
    union { float f; unsigned u; } x, y; x.f = a; y.f = b;
    return ((x.u + 0x8000u) >> 16) | ((y.u + 0x8000u) & 0xffff0000u);
}
__device__ __forceinline__ void cp16(const void* g, void* lds) {
    __builtin_amdgcn_global_load_lds(
        (const __attribute__((address_space(1))) void*)g,
        (__attribute__((address_space(3))) void*)lds, 16, 0, 0);
}

// ---- pre-pass (unchanged from R4) ----
// y==0: K fp32 -> Kb bf16 [bkvh][s][chunk^(s&7) swizzled d]   (coalesced)
// y==1: V fp32 -> Vt bf16 [bkvh][d][s64-block][chunk^(d&7)][k'&7]
//       where k' = (kv&15)*4 + (kv>>4); transposed via LDS, 16B writes.
__global__ __launch_bounds__(256, 4)
void prepack(const float* __restrict__ K, const float* __restrict__ V,
             unsigned short* __restrict__ Kb, unsigned short* __restrict__ Vt) {
    if (blockIdx.y == 0) {
        const long long flat = (long long)blockIdx.x * 2048 + threadIdx.x * 8;
        const int s = (int)(flat >> 7) & (S_LEN - 1);
        const int d0 = (int)flat & 127;
        const float* p = K + flat;
        float4 x = *(const float4*)p;
        float4 y = *(const float4*)(p + 4);
        const int cs = (d0 >> 3) ^ (s & 7);
        uint4 o;
        o.x = pk2(x.x, x.y); o.y = pk2(x.z, x.w);
        o.z = pk2(y.x, y.y); o.w = pk2(y.z, y.w);
        *(uint4*)(Kb + (flat & ~127LL) + cs * 8) = o;
    } else {
        const int x = blockIdx.x;
        const int bkvh = x >> 7, sblk = (x >> 2) & 31, q = x & 3;
        const int tid = threadIdx.x;
        __shared__ unsigned Lt[64][17];
        const float* base = V + (size_t)bkvh * S_LEN * DH + (size_t)sblk * 64 * DH + q * 32;
#pragma unroll
        for (int j = 0; j < 2; ++j) {
            const int e = tid + j * 256;
            const int s = e >> 3, c4 = e & 7;
            float4 v = *(const float4*)(base + (size_t)s * DH + c4 * 4);
            Lt[s][c4 * 2]     = pk2(v.x, v.y);
            Lt[s][c4 * 2 + 1] = pk2(v.z, v.w);
        }
        __syncthreads();
        const unsigned short* lt = (const unsigned short*)&Lt[0][0]; // stride 34
        const int d_loc = tid >> 3, pc = tid & 7;
        const int d = q * 32 + d_loc;
        const int c_log = pc ^ (d & 7);
        unsigned short vv[8];
#pragma unroll
        for (int j = 0; j < 8; ++j) {
            const int kp = c_log * 8 + j;
            const int kv = (kp & 3) * 16 + (kp >> 2);
            vv[j] = lt[kv * 34 + d_loc];
        }
        uint4 o;
        o.x = (unsigned)vv[0] | ((unsigned)vv[1] << 16);
        o.y = (unsigned)vv[2] | ((unsigned)vv[3] << 16);
        o.z = (unsigned)vv[4] | ((unsigned)vv[5] << 16);
        o.w = (unsigned)vv[6] | ((unsigned)vv[7] << 16);
        *(uint4*)(Vt + (size_t)bkvh * S_LEN * DH + (size_t)d * S_LEN + sblk * 64 + pc * 8) = o;
    }
}

__global__ __launch_bounds__(256, 2)
void attn_fwd(const float* __restrict__ Q,
              const unsigned short* __restrict__ Kb,
              const unsigned short* __restrict__ Vtg,
              float* __restrict__ O) {
    // 1D grid, (qt, 15-qt) pairing -> every CU gets exactly 34 tile-rounds
    const int n  = blockIdx.x;
    const int x  = n & 15;
    const int h  = (n >> 4) & 15;
    const int b  = n >> 8;
    const int qt = b ? x : (NQT - 1 - x);
    const int kvh = h >> 2;

    const int tid  = threadIdx.x;
    const int w    = tid >> 6;
    const int lane = tid & 63;
    const int quad = lane >> 4;
    const int l16  = lane & 15;
    const int swz  = l16 & 7;

    __shared__ alignas(16) unsigned short Kl[2][TK][DH];  // 32 KB (dbuf DMA image)
    __shared__ alignas(16) unsigned short Vl[DH][TK];     // 16 KB (DMA image)
    __shared__ alignas(16) unsigned short Pl[TQ][TK];     // 16 KB, chunk-swizzled

    const unsigned short* kb = Kb  + ((size_t)b * NKVH + kvh) * (size_t)(S_LEN * DH);
    const unsigned short* vb = Vtg + ((size_t)b * NKVH + kvh) * (size_t)(S_LEN * DH);

    // ---- Q fragments (A layout), scaled by 1/sqrt(D)*log2e ----
    const int wq0 = qt * TQ + w * 32;
    short8 aq[2][4];
#pragma unroll
    for (int sub = 0; sub < 2; ++sub) {
        const float* qp = Q + (((size_t)b * NH + h) * S_LEN + wq0 + sub * 16 + l16) * DH;
#pragma unroll
        for (int dc = 0; dc < 4; ++dc) {
            float4 xx = *(const float4*)(qp + dc * 32 + quad * 8);
            float4 yy = *(const float4*)(qp + dc * 32 + quad * 8 + 4);
            union { unsigned u[4]; short8 s; } t;
            t.u[0] = pk2(xx.x * QSCALE, xx.y * QSCALE);
            t.u[1] = pk2(xx.z * QSCALE, xx.w * QSCALE);
            t.u[2] = pk2(yy.x * QSCALE, yy.y * QSCALE);
            t.u[3] = pk2(yy.z * QSCALE, yy.w * QSCALE);
            aq[sub][dc] = t.s;
        }
    }

    f32x4 o[2][8];
#pragma unroll
    for (int sub = 0; sub < 2; ++sub)
#pragma unroll
        for (int ch = 0; ch < 8; ++ch) o[sub][ch] = (f32x4){0.f, 0.f, 0.f, 0.f};
    float lsum[2][4];
#pragma unroll
    for (int sub = 0; sub < 2; ++sub)
#pragma unroll
        for (int r = 0; r < 4; ++r) lsum[sub][r] = 0.f;

    const int nt  = 2 * qt + 2;
    const int ntw = 2 * qt + 1 + (w >> 1);

    // ---- prologue: DMA K tile 0, publish ----
#pragma unroll
    for (int i = 0; i < 4; ++i)
        cp16((const char*)kb + w * 4096 + i * 1024 + lane * 16,
             (char*)&Kl[0][0][0] + w * 4096 + i * 1024);
    __syncthreads();

    for (int t = 0; t < nt; ++t) {
        const int j0 = t * TK;
        // ---- A: issue V(t) and K(t+1); drained at barrier X after QK+softmax ----
#pragma unroll
        for (int i = 0; i < 4; ++i) {
            const int row  = w * 32 + i * 8 + (lane >> 3);
            const int colB = (lane & 7) * 16;
            cp16((const char*)vb + (size_t)row * (S_LEN * 2) + j0 * 2 + colB,
                 (char*)&Vl[0][0] + w * 4096 + i * 1024);
        }
        if (t + 1 < nt) {
            const char* ks = (const char*)(kb + (size_t)(j0 + TK) * DH);
            char* kd = (char*)&Kl[(t + 1) & 1][0][0];
#pragma unroll
            for (int i = 0; i < 4; ++i)
                cp16(ks + w * 4096 + i * 1024 + lane * 16, kd + w * 4096 + i * 1024);
        }

        const unsigned short (*Kc)[DH] = Kl[t & 1];
        const bool active = (t < ntw);
        const bool diag = (t == ntw - 1);
        f32x4 s[2][4];

        if (active) {
            // ---- QK^T on K(t) (published at previous round's X) ----
#pragma unroll
            for (int sub = 0; sub < 2; ++sub)
#pragma unroll
                for (int k4 = 0; k4 < 4; ++k4) s[sub][k4] = (f32x4){0.f, 0.f, 0.f, 0.f};
#pragma unroll
            for (int dc = 0; dc < 4; ++dc) {
#pragma unroll
                for (int k4 = 0; k4 < 4; ++k4) {
                    short8 bk = *(const short8*)&Kc[k4 * 16 + l16][((dc * 4 + quad) ^ swz) * 8];
                    s[0][k4] = __builtin_amdgcn_mfma_f32_16x16x32_bf16(aq[0][dc], bk, s[0][k4], 0, 0, 0);
                    s[1][k4] = __builtin_amdgcn_mfma_f32_16x16x32_bf16(aq[1][dc], bk, s[1][k4], 0, 0, 0);
                }
            }
            // ---- fixed-shift softmax; P[prow][k'] with chunk^(prow&7) swizzle ----
#pragma unroll
            for (int sub = 0; sub < 2; ++sub) {
                const int rb = wq0 + sub * 16 + quad * 4;
#pragma unroll
                for (int r = 0; r < 4; ++r) {
                    float v0 = s[sub][0][r], v1 = s[sub][1][r];
                    float v2 = s[sub][2][r], v3 = s[sub][3][r];
                    if (diag) {
                        const int row = rb + r;
                        if (j0 + l16      > row) v0 = -1e30f;
                        if (j0 + 16 + l16 > row) v1 = -1e30f;
                        if (j0 + 32 + l16 > row) v2 = -1e30f;
                        if (j0 + 48 + l16 > row) v3 = -1e30f;
                    }
                    float p0 = EX2(v0), p1 = EX2(v1), p2 = EX2(v2), p3 = EX2(v3);
                    lsum[sub][r] += (p0 + p1) + (p2 + p3);
                    const int prow = w * 32 + sub * 16 + quad * 4 + r;
                    const int chs = (l16 >> 1) ^ (prow & 7);
                    *(uint2*)&Pl[prow][chs * 8 + (l16 & 1) * 4] =
                        make_uint2(pk2(p0, p1), pk2(p2, p3));
                }
            }
        }

        __syncthreads();   // X: publish V(t) (+ drain K(t+1)), overlapped by QK+softmax

        if (active) {
            // ---- PV: O(32x128) += P(32x64) . V(64x128) over permuted k' ----
#pragma unroll
            for (int kc = 0; kc < 2; ++kc) {
                const int pr0 = w * 32 + l16;
                short8 ap0 = *(const short8*)&Pl[pr0][(((kc * 4 + quad) ^ swz)) * 8];
                short8 ap1 = *(const short8*)&Pl[pr0 + 16][(((kc * 4 + quad) ^ swz)) * 8];
#pragma unroll
                for (int ch = 0; ch < 8; ++ch) {
                    short8 bv = *(const short8*)&Vl[ch * 16 + l16][((kc * 4 + quad) ^ swz) * 8];
                    o[0][ch] = __builtin_amdgcn_mfma_f32_16x16x32_bf16(ap0, bv, o[0][ch], 0, 0, 0);
                    o[1][ch] = __builtin_amdgcn_mfma_f32_16x16x32_bf16(ap1, bv, o[1][ch], 0, 0, 0);
                }
            }
        }

        __syncthreads();   // C2: all PV reads of Vl/P done before next round's DMA
    }

    // ---- epilogue: reduce l across 16 lanes, divide, store [B,S,H*D] ----
#pragma unroll
    for (int sub = 0; sub < 2; ++sub) {
#pragma unroll
        for (int r = 0; r < 4; ++r) {
            float rs = lsum[sub][r];
            rs += __shfl_xor(rs, 1);
            rs += __shfl_xor(rs, 2);
            rs += __shfl_xor(rs, 4);
            rs += __shfl_xor(rs, 8);
            const float invl = 1.f / rs;
            const int row = wq0 + sub * 16 + quad * 4 + r;
            float* op = O + ((size_t)b * S_LEN + row) * (NH * DH) + h * DH;
#pragma unroll
            for (int ch = 0; ch < 8; ++ch)
                op[ch * 16 + l16] = o[sub][ch][r] * invl;
        }
    }
}

extern "C" void kernel_launch(void* const* d_in, const int* in_sizes, int n_in,
                              void* d_out, int out_size, void* d_ws, size_t ws_size,
                              hipStream_t stream) {
    const float* Q = (const float*)d_in[0];
    const float* K = (const float*)d_in[1];
    const float* V = (const float*)d_in[2];
    float* O = (float*)d_out;
    unsigned short* Kb = (unsigned short*)d_ws;                       // 4 MB
    unsigned short* Vt = Kb + (size_t)NB * NKVH * S_LEN * DH;         // 4 MB
    dim3 pgrid(NB * NKVH * (S_LEN / 16), 2);
    prepack<<<pgrid, 256, 0, stream>>>(K, V, Kb, Vt);
    attn_fwd<<<dim3(512), 256, 0, stream>>>(Q, Kb, Vt, O);
}

// Round 6
// 154.844 us; speedup vs baseline: 1.0240x; 1.0240x over previous
//
#include <hip/hip_runtime.h>

// Causal GQA attention, MI355X (gfx950). B=2,H=16,Hkv=4,S=2048,D=128 fp32.
// R6: (1) XCD-aware block mapping: blockIdx%8 == (b,kvh) -> each XCD's L2
// holds exactly one 2MB K/V image (was 16MB working set -> 42GB L2-miss
// traffic). (2) KV-split of heavy q-tiles (qt>=5) into lower/upper halves --
// fixed-shift softmax has no running max, so partials combine as
// (oa+ob)/(la+lb). Hand-packed LPT schedule: every block 14-19 rounds
// (was 2-32; wall time = heaviest BLOCK since co-resident blocks run
// concurrently). Partials (bf16 o, f32 l) in d_ws; combine kernel normalizes.
// Pipeline per round unchanged from R5 (K dbuf, V single, P swizzled, 64KB).

#define S_LEN 2048
#define DH    128
#define NH    16
#define NKVH  4
#define NB    2
#define TQ    128
#define TK    64
#define NQT   (S_LEN / TQ)   // 16
#define QSCALE 0.12752749610559243f   // (1/sqrt(128)) * log2(e)
#define NSPLIT 11            // qt 5..15 are split

typedef __attribute__((ext_vector_type(8))) short short8;
typedef __attribute__((ext_vector_type(4))) float f32x4;

#if __has_builtin(__builtin_amdgcn_exp2f)
#define EX2(x) __builtin_amdgcn_exp2f(x)
#else
#define EX2(x) exp2f(x)
#endif

// Per-head schedule: 16 CU-slots x up to 2 items. Item = (qt, mode):
// mode 0 = lower KV half [0,qt+1), 1 = upper half [qt+1,2qt+2), 2 = whole
// tile, -1 = none. Loads (rounds): 16,16,15,15,16,14,19,17,18,18,18,18,18,18,18,18.
__constant__ signed char SLOT_QT[16][2] = {
    {15,-1},{15,-1},{14,-1},{14,-1},{13, 0},{13,-1},{12, 2},{12, 1},
    {11, 5},{11, 5},{10, 6},{10, 6},{ 9, 7},{ 9, 7},{ 4, 3},{ 8, 8}};
__constant__ signed char SLOT_MODE[16][2] = {
    { 0,-1},{ 1,-1},{ 0,-1},{ 1,-1},{ 0, 2},{ 1,-1},{ 0, 2},{ 1, 2},
    { 0, 0},{ 1, 1},{ 0, 0},{ 1, 1},{ 0, 0},{ 1, 1},{ 2, 2},{ 0, 1}};

__device__ __forceinline__ unsigned short bf1(float a) {
    union { float f; unsigned u; } x; x.f = a;
    return (unsigned short)((x.u + 0x8000u) >> 16);
}
__device__ __forceinline__ float bf2f(unsigned short a) {
    union { float f; unsigned u; } x; x.u = (unsigned)a << 16; return x.f;
}
__device__ __forceinline__ unsigned pk2(float a, float b) {
    union { float f; unsigned u; } x, y; x.f = a; y.f = b;
    return ((x.u + 0x8000u) >> 16) | ((y.u + 0x8000u) & 0xffff0000u);
}
__device__ __forceinline__ void cp16(const void* g, void* lds) {
    __builtin_amdgcn_global_load_lds(
        (const __attribute__((address_space(1))) void*)g,
        (__attribute__((address_space(3))) void*)lds, 16, 0, 0);
}

// ---- pre-pass (unchanged from R4) ----
__global__ __launch_bounds__(256, 4)
void prepack(const float* __restrict__ K, const float* __restrict__ V,
             unsigned short* __restrict__ Kb, unsigned short* __restrict__ Vt) {
    if (blockIdx.y == 0) {
        const long long flat = (long long)blockIdx.x * 2048 + threadIdx.x * 8;
        const int s = (int)(flat >> 7) & (S_LEN - 1);
        const int d0 = (int)flat & 127;
        const float* p = K + flat;
        float4 x = *(const float4*)p;
        float4 y = *(const float4*)(p + 4);
        const int cs = (d0 >> 3) ^ (s & 7);
        uint4 o;
        o.x = pk2(x.x, x.y); o.y = pk2(x.z, x.w);
        o.z = pk2(y.x, y.y); o.w = pk2(y.z, y.w);
        *(uint4*)(Kb + (flat & ~127LL) + cs * 8) = o;
    } else {
        const int x = blockIdx.x;
        const int bkvh = x >> 7, sblk = (x >> 2) & 31, q = x & 3;
        const int tid = threadIdx.x;
        __shared__ unsigned Lt[64][17];
        const float* base = V + (size_t)bkvh * S_LEN * DH + (size_t)sblk * 64 * DH + q * 32;
#pragma unroll
        for (int j = 0; j < 2; ++j) {
            const int e = tid + j * 256;
            const int s = e >> 3, c4 = e & 7;
            float4 v = *(const float4*)(base + (size_t)s * DH + c4 * 4);
            Lt[s][c4 * 2]     = pk2(v.x, v.y);
            Lt[s][c4 * 2 + 1] = pk2(v.z, v.w);
        }
        __syncthreads();
        const unsigned short* lt = (const unsigned short*)&Lt[0][0]; // stride 34
        const int d_loc = tid >> 3, pc = tid & 7;
        const int d = q * 32 + d_loc;
        const int c_log = pc ^ (d & 7);
        unsigned short vv[8];
#pragma unroll
        for (int j = 0; j < 8; ++j) {
            const int kp = c_log * 8 + j;
            const int kv = (kp & 3) * 16 + (kp >> 2);
            vv[j] = lt[kv * 34 + d_loc];
        }
        uint4 o;
        o.x = (unsigned)vv[0] | ((unsigned)vv[1] << 16);
        o.y = (unsigned)vv[2] | ((unsigned)vv[3] << 16);
        o.z = (unsigned)vv[4] | ((unsigned)vv[5] << 16);
        o.w = (unsigned)vv[6] | ((unsigned)vv[7] << 16);
        *(uint4*)(Vt + (size_t)bkvh * S_LEN * DH + (size_t)d * S_LEN + sblk * 64 + pc * 8) = o;
    }
}

__global__ __launch_bounds__(256, 2)
void attn_fwd(const float* __restrict__ Q,
              const unsigned short* __restrict__ Kb,
              const unsigned short* __restrict__ Vtg,
              float* __restrict__ O,
              unsigned short* __restrict__ OP,   // bf16 partial o
              float* __restrict__ LP) {          // f32 partial l
    // blockIdx.x in [0,512): xcd = n&7 = b*4+kvh (L2 locality);
    // j = n>>3 in [0,64): h_local = j>>4, slot = j&15.
    const int n   = blockIdx.x;
    const int xcd = n & 7;
    const int b   = xcd >> 2;
    const int kvh = xcd & 3;
    const int j   = n >> 3;
    const int hl  = j >> 4;
    const int slot = j & 15;
    const int h   = kvh * 4 + hl;
    const int hh  = xcd * 4 + hl;     // 0..31

    const int tid  = threadIdx.x;
    const int w    = tid >> 6;
    const int lane = tid & 63;
    const int quad = lane >> 4;
    const int l16  = lane & 15;
    const int swz  = l16 & 7;

    __shared__ alignas(16) unsigned short Kl[2][TK][DH];  // 32 KB
    __shared__ alignas(16) unsigned short Vl[DH][TK];     // 16 KB
    __shared__ alignas(16) unsigned short Pl[TQ][TK];     // 16 KB

    const unsigned short* kb = Kb  + (size_t)xcd * (S_LEN * DH);
    const unsigned short* vb = Vtg + (size_t)xcd * (S_LEN * DH);

    for (int it = 0; it < 2; ++it) {
        const int qt   = SLOT_QT[slot][it];
        const int mode = SLOT_MODE[slot][it];
        if (mode < 0) continue;                    // block-uniform
        const int nt   = 2 * qt + 2;
        const int t_lo = (mode == 1) ? (qt + 1) : 0;
        const int t_hi = (mode == 0) ? (qt + 1) : nt;
        const int Tw   = 2 * qt + 1 + (w >> 1);    // per-wave causal limit

        // ---- Q fragments (A layout), scaled by 1/sqrt(D)*log2e ----
        const int wq0 = qt * TQ + w * 32;
        short8 aq[2][4];
#pragma unroll
        for (int sub = 0; sub < 2; ++sub) {
            const float* qp = Q + (((size_t)b * NH + h) * S_LEN + wq0 + sub * 16 + l16) * DH;
#pragma unroll
            for (int dc = 0; dc < 4; ++dc) {
                float4 xx = *(const float4*)(qp + dc * 32 + quad * 8);
                float4 yy = *(const float4*)(qp + dc * 32 + quad * 8 + 4);
                union { unsigned u[4]; short8 s; } tt;
                tt.u[0] = pk2(xx.x * QSCALE, xx.y * QSCALE);
                tt.u[1] = pk2(xx.z * QSCALE, xx.w * QSCALE);
                tt.u[2] = pk2(yy.x * QSCALE, yy.y * QSCALE);
                tt.u[3] = pk2(yy.z * QSCALE, yy.w * QSCALE);
                aq[sub][dc] = tt.s;
            }
        }

        f32x4 o[2][8];
#pragma unroll
        for (int sub = 0; sub < 2; ++sub)
#pragma unroll
            for (int ch = 0; ch < 8; ++ch) o[sub][ch] = (f32x4){0.f, 0.f, 0.f, 0.f};
        float lsum[2][4];
#pragma unroll
        for (int sub = 0; sub < 2; ++sub)
#pragma unroll
            for (int r = 0; r < 4; ++r) lsum[sub][r] = 0.f;

        // ---- prologue: DMA K tile t_lo, publish ----
#pragma unroll
        for (int i = 0; i < 4; ++i)
            cp16((const char*)(kb + (size_t)t_lo * TK * DH) + w * 4096 + i * 1024 + lane * 16,
                 (char*)&Kl[t_lo & 1][0][0] + w * 4096 + i * 1024);
        __syncthreads();

        for (int t = t_lo; t < t_hi; ++t) {
            const int j0 = t * TK;
            // issue V(t) and K(t+1); drained at barrier X after QK+softmax
#pragma unroll
            for (int i = 0; i < 4; ++i) {
                const int row  = w * 32 + i * 8 + (lane >> 3);
                const int colB = (lane & 7) * 16;
                cp16((const char*)vb + (size_t)row * (S_LEN * 2) + j0 * 2 + colB,
                     (char*)&Vl[0][0] + w * 4096 + i * 1024);
            }
            if (t + 1 < t_hi) {
                const char* ks = (const char*)(kb + (size_t)(j0 + TK) * DH);
                char* kd = (char*)&Kl[(t + 1) & 1][0][0];
#pragma unroll
                for (int i = 0; i < 4; ++i)
                    cp16(ks + w * 4096 + i * 1024 + lane * 16, kd + w * 4096 + i * 1024);
            }

            const unsigned short (*Kc)[DH] = Kl[t & 1];
            const bool active = (t < Tw);
            const bool diag = (t == Tw - 1);
            f32x4 s[2][4];

            if (active) {
                // ---- QK^T on K(t) ----
#pragma unroll
                for (int sub = 0; sub < 2; ++sub)
#pragma unroll
                    for (int k4 = 0; k4 < 4; ++k4) s[sub][k4] = (f32x4){0.f, 0.f, 0.f, 0.f};
#pragma unroll
                for (int dc = 0; dc < 4; ++dc) {
#pragma unroll
                    for (int k4 = 0; k4 < 4; ++k4) {
                        short8 bk = *(const short8*)&Kc[k4 * 16 + l16][((dc * 4 + quad) ^ swz) * 8];
                        s[0][k4] = __builtin_amdgcn_mfma_f32_16x16x32_bf16(aq[0][dc], bk, s[0][k4], 0, 0, 0);
                        s[1][k4] = __builtin_amdgcn_mfma_f32_16x16x32_bf16(aq[1][dc], bk, s[1][k4], 0, 0, 0);
                    }
                }
                // ---- fixed-shift softmax; P swizzled ----
#pragma unroll
                for (int sub = 0; sub < 2; ++sub) {
                    const int rb = wq0 + sub * 16 + quad * 4;
#pragma unroll
                    for (int r = 0; r < 4; ++r) {
                        float v0 = s[sub][0][r], v1 = s[sub][1][r];
                        float v2 = s[sub][2][r], v3 = s[sub][3][r];
                        if (diag) {
                            const int row = rb + r;
                            if (j0 + l16      > row) v0 = -1e30f;
                            if (j0 + 16 + l16 > row) v1 = -1e30f;
                            if (j0 + 32 + l16 > row) v2 = -1e30f;
                            if (j0 + 48 + l16 > row) v3 = -1e30f;
                        }
                        float p0 = EX2(v0), p1 = EX2(v1), p2 = EX2(v2), p3 = EX2(v3);
                        lsum[sub][r] += (p0 + p1) + (p2 + p3);
                        const int prow = w * 32 + sub * 16 + quad * 4 + r;
                        const int chs = (l16 >> 1) ^ (prow & 7);
                        *(uint2*)&Pl[prow][chs * 8 + (l16 & 1) * 4] =
                            make_uint2(pk2(p0, p1), pk2(p2, p3));
                    }
                }
            }

            __syncthreads();   // X: publish V(t) (+K(t+1)); drain overlapped by QK

            if (active) {
                // ---- PV over permuted k' ----
#pragma unroll
                for (int kc = 0; kc < 2; ++kc) {
                    const int pr0 = w * 32 + l16;
                    short8 ap0 = *(const short8*)&Pl[pr0][(((kc * 4 + quad) ^ swz)) * 8];
                    short8 ap1 = *(const short8*)&Pl[pr0 + 16][(((kc * 4 + quad) ^ swz)) * 8];
#pragma unroll
                    for (int ch = 0; ch < 8; ++ch) {
                        short8 bv = *(const short8*)&Vl[ch * 16 + l16][((kc * 4 + quad) ^ swz) * 8];
                        o[0][ch] = __builtin_amdgcn_mfma_f32_16x16x32_bf16(ap0, bv, o[0][ch], 0, 0, 0);
                        o[1][ch] = __builtin_amdgcn_mfma_f32_16x16x32_bf16(ap1, bv, o[1][ch], 0, 0, 0);
                    }
                }
            }

            __syncthreads();   // C2: PV reads done before next round's DMA
        }

        // ---- epilogue ----
        if (mode == 2) {
#pragma unroll
            for (int sub = 0; sub < 2; ++sub) {
#pragma unroll
                for (int r = 0; r < 4; ++r) {
                    float rs = lsum[sub][r];
                    rs += __shfl_xor(rs, 1);
                    rs += __shfl_xor(rs, 2);
                    rs += __shfl_xor(rs, 4);
                    rs += __shfl_xor(rs, 8);
                    const float invl = 1.f / rs;
                    const int row = wq0 + sub * 16 + quad * 4 + r;
                    float* op = O + ((size_t)b * S_LEN + row) * (NH * DH) + h * DH;
#pragma unroll
                    for (int ch = 0; ch < 8; ++ch)
                        op[ch * 16 + l16] = o[sub][ch][r] * invl;
                }
            }
        } else {
            // partial: o (bf16, unnormalized) + l (f32) to workspace
            const size_t pbase = ((size_t)(hh * NSPLIT + (qt - 5)) * 2 + mode) * (128 * 128);
            unsigned short* opp = OP + pbase;
            float* lpp = LP + ((size_t)(hh * NSPLIT + (qt - 5)) * 2 + mode) * 128;
#pragma unroll
            for (int sub = 0; sub < 2; ++sub) {
#pragma unroll
                for (int r = 0; r < 4; ++r) {
                    float rs = lsum[sub][r];
                    rs += __shfl_xor(rs, 1);
                    rs += __shfl_xor(rs, 2);
                    rs += __shfl_xor(rs, 4);
                    rs += __shfl_xor(rs, 8);
                    const int lrow = w * 32 + sub * 16 + quad * 4 + r;
                    if (l16 == 0) lpp[lrow] = rs;
#pragma unroll
                    for (int ch = 0; ch < 8; ++ch)
                        opp[(size_t)lrow * 128 + ch * 16 + l16] = bf1(o[sub][ch][r]);
                }
            }
        }
        __syncthreads();   // LDS reuse safety between items
    }
}

// ---- combine: O[rows of split tiles] = (oa+ob)/(la+lb) ----
__global__ __launch_bounds__(256, 4)
void combine(const unsigned short* __restrict__ OP, const float* __restrict__ LP,
             float* __restrict__ O) {
    const int cb = blockIdx.x;          // 32*NSPLIT blocks
    const int hh = cb / NSPLIT, qi = cb - hh * NSPLIT;
    const int qt = qi + 5;
    const int b = hh >> 4, kvh = (hh >> 2) & 3, hl = hh & 3, h = kvh * 4 + hl;
    __shared__ float Linv[128];
    if (threadIdx.x < 128) {
        const size_t lb = (size_t)(hh * NSPLIT + qi) * 2 * 128;
        Linv[threadIdx.x] = 1.f / (LP[lb + threadIdx.x] + LP[lb + 128 + threadIdx.x]);
    }
    __syncthreads();
    const unsigned short* pa = OP + (size_t)(hh * NSPLIT + qi) * 2 * 16384;
    const unsigned short* pb = pa + 16384;
    float* ob = O + ((size_t)b * S_LEN + qt * 128) * (NH * DH) + h * DH;
#pragma unroll
    for (int i = 0; i < 16; ++i) {
        const int flat = i * 1024 + threadIdx.x * 4;
        const int row = flat >> 7, d = flat & 127;
        ushort4 a = *(const ushort4*)(pa + flat);
        ushort4 bq = *(const ushort4*)(pb + flat);
        const float inv = Linv[row];
        float4 r;
        r.x = (bf2f(a.x) + bf2f(bq.x)) * inv;
        r.y = (bf2f(a.y) + bf2f(bq.y)) * inv;
        r.z = (bf2f(a.z) + bf2f(bq.z)) * inv;
        r.w = (bf2f(a.w) + bf2f(bq.w)) * inv;
        *(float4*)(ob + (size_t)row * (NH * DH) + d) = r;
    }
}

extern "C" void kernel_launch(void* const* d_in, const int* in_sizes, int n_in,
                              void* d_out, int out_size, void* d_ws, size_t ws_size,
                              hipStream_t stream) {
    const float* Q = (const float*)d_in[0];
    const float* K = (const float*)d_in[1];
    const float* V = (const float*)d_in[2];
    float* O = (float*)d_out;
    unsigned short* Kb = (unsigned short*)d_ws;                        // 4 MB
    unsigned short* Vt = Kb + (size_t)NB * NKVH * S_LEN * DH;          // 4 MB
    unsigned short* OP = Vt + (size_t)NB * NKVH * S_LEN * DH;          // 22 MB bf16
    float* LP = (float*)(OP + (size_t)32 * NSPLIT * 2 * 128 * 128);    // 352 KB
    dim3 pgrid(NB * NKVH * (S_LEN / 16), 2);
    prepack<<<pgrid, 256, 0, stream>>>(K, V, Kb, Vt);
    attn_fwd<<<dim3(512), 256, 0, stream>>>(Q, Kb, Vt, O, OP, LP);
    combine<<<dim3(32 * NSPLIT), 256, 0, stream>>>(OP, LP, O);
}